// Round 4
// baseline (5267.392 us; speedup 1.0000x reference)
//
#include <hip/hip_runtime.h>

#define DIMC 768
#define NQKV 2304
#define NPOS 32768

// C[m][c] = A[m][0:768] @ B[0:768][c] + bias[c]; all fp32.
// A ld=768, B ld=ldn, C ld=ldn. 64x64 output tile per block, 256 threads;
// wave tm owns rows tm*16..+15, lane tj owns column tj. grid=(ldn/64, rows/64).
__global__ __launch_bounds__(256) void gemm_f32(
    const float* __restrict__ A, const float* __restrict__ B,
    const float* __restrict__ bias, float* __restrict__ C, int ldn)
{
    __shared__ __align__(16) float AsT[64 * 64];  // [k][m]
    __shared__ __align__(16) float Bs[64 * 64];   // [k][j]
    const int t  = threadIdx.x;
    const int cb = blockIdx.x;
    const int rb = blockIdx.y;
    const int tm = t >> 6, tj = t & 63;
    const int sm = t >> 2, q4 = t & 3;

    float acc[16];
    #pragma unroll
    for (int i = 0; i < 16; ++i) acc[i] = 0.f;

    const float* arow = A + (size_t)(rb * 64 + sm) * DIMC + q4 * 16;

    for (int kb = 0; kb < 12; ++kb) {
        __syncthreads();
        {   // A tile -> transposed fp32 LDS: AsT[k][m] = A[m][k]
            const float4* p = (const float4*)(arow + kb * 64);
            float4 a0 = p[0], a1 = p[1], a2 = p[2], a3 = p[3];
            float vv[16] = {a0.x, a0.y, a0.z, a0.w, a1.x, a1.y, a1.z, a1.w,
                            a2.x, a2.y, a2.z, a2.w, a3.x, a3.y, a3.z, a3.w};
            #pragma unroll
            for (int i = 0; i < 16; ++i)
                AsT[(q4 * 16 + i) * 64 + sm] = vv[i];
        }
        {   // B tile fp32 LDS: Bs[k][j] = B[k][cb*64+j]
            const float4* p = (const float4*)(B + (size_t)(kb * 64 + sm) * ldn + cb * 64 + q4 * 16);
            float4 b0 = p[0], b1 = p[1], b2 = p[2], b3 = p[3];
            float4* q = (float4*)&Bs[sm * 64 + q4 * 16];
            q[0] = b0; q[1] = b1; q[2] = b2; q[3] = b3;
        }
        __syncthreads();
        #pragma unroll 4
        for (int kk = 0; kk < 64; ++kk) {
            const float4* xp = (const float4*)&AsT[kk * 64 + tm * 16]; // wave-broadcast
            float4 x0 = xp[0], x1 = xp[1], x2 = xp[2], x3 = xp[3];
            float xr[16] = {x0.x, x0.y, x0.z, x0.w, x1.x, x1.y, x1.z, x1.w,
                            x2.x, x2.y, x2.z, x2.w, x3.x, x3.y, x3.z, x3.w};
            float bv = Bs[kk * 64 + tj];
            #pragma unroll
            for (int i = 0; i < 16; ++i) acc[i] = fmaf(xr[i], bv, acc[i]);
        }
    }
    const int c = cb * 64 + tj;
    float bb = bias[c];
    #pragma unroll
    for (int i = 0; i < 16; ++i) {
        size_t idx = (size_t)(rb * 64 + tm * 16 + i) * ldn + c;
        C[idx] = acc[i] + bb;
    }
}

// Head-attention per position p: qkv row = [q(12x64) | k(12x64) | v(12x64)] fp32.
// S[h][g] = 0.125 * q_h . k_g ; A = softmax_g(S); out[h*64+d] = sum_g A[h,g] v[g*64+d].
// One wave per position; 4 positions per block. sum is fp32.
__global__ __launch_bounds__(256) void headattn(
    const float* __restrict__ qkv, float* __restrict__ sum, int accumulate)
{
    __shared__ float qs[4][12 * 65];
    __shared__ float ks[4][12 * 65];
    __shared__ float vs[4][12 * 65];
    __shared__ float Sld[4][144];
    const int t = threadIdx.x, wv = t >> 6, lane = t & 63;
    const int p = blockIdx.x * 4 + wv;
    const float* row = qkv + (size_t)p * NQKV;

    // stage: 576 float4 per position; lane handles 9
    #pragma unroll
    for (int j = 0; j < 9; ++j) {
        int u4 = lane + 64 * j;               // 0..575
        float4 d4 = *(const float4*)(row + u4 * 4);
        int c = u4 * 4;
        int s = c / 768, r = c % 768;
        int h = r >> 6, d = r & 63;
        float* dst = (s == 0) ? qs[wv] : (s == 1) ? ks[wv] : vs[wv];
        dst[h * 65 + d + 0] = d4.x;
        dst[h * 65 + d + 1] = d4.y;
        dst[h * 65 + d + 2] = d4.z;
        dst[h * 65 + d + 3] = d4.w;
    }
    __syncthreads();
    // scores S[h][g]
    for (int e = lane; e < 144; e += 64) {
        int h = e / 12, g = e - h * 12;
        float s = 0.f;
        #pragma unroll 8
        for (int d = 0; d < 64; ++d)
            s = fmaf(qs[wv][h * 65 + d], ks[wv][g * 65 + d], s);
        Sld[wv][e] = s * 0.125f;
    }
    __syncthreads();
    // softmax over g; lanes 0..11 each own a row h=lane
    if (lane < 12) {
        float m = -1e30f;
        #pragma unroll
        for (int g = 0; g < 12; ++g) m = fmaxf(m, Sld[wv][lane * 12 + g]);
        float ex[12]; float ssum = 0.f;
        #pragma unroll
        for (int g = 0; g < 12; ++g) { ex[g] = __expf(Sld[wv][lane * 12 + g] - m); ssum += ex[g]; }
        float inv = 1.f / ssum;
        #pragma unroll
        for (int g = 0; g < 12; ++g) Sld[wv][lane * 12 + g] = ex[g] * inv;
    }
    __syncthreads();
    // out: lane = d
    float* orow = sum + (size_t)p * DIMC;
    #pragma unroll
    for (int h = 0; h < 12; ++h) {
        float o = 0.f;
        #pragma unroll
        for (int g = 0; g < 12; ++g)
            o = fmaf(Sld[wv][h * 12 + g], vs[wv][g * 65 + lane], o);
        int idx = h * 64 + lane;
        if (accumulate) o += orow[idx];
        orow[idx] = o;
    }
}

extern "C" void kernel_launch(void* const* d_in, const int* in_sizes, int n_in,
                              void* d_out, int out_size, void* d_ws, size_t ws_size,
                              hipStream_t stream) {
    const float* x  = (const float*)d_in[0];
    const float* wh = (const float*)d_in[1];
    const float* bh = (const float*)d_in[2];
    const float* ww = (const float*)d_in[3];
    const float* bw = (const float*)d_in[4];
    const float* wp = (const float*)d_in[5];
    const float* bp = (const float*)d_in[6];
    float* out = (float*)d_out;                 // reference output dtype: float32

    // ws per slab of S positions (fp32): qkv (S*2304) | sum (S*768) = S*12288 B
    auto need = [](size_t S) { return S * 12288; };
    size_t S;
    if      (ws_size >= need(32768)) S = 32768;
    else if (ws_size >= need(8192))  S = 8192;
    else if (ws_size >= need(2048))  S = 2048;
    else if (ws_size >= need(512))   S = 512;
    else                             S = 128;

    float* qkvws = (float*)d_ws;
    float* sumws = qkvws + S * NQKV;

    for (size_t base = 0; base < NPOS; base += S) {
        const float* xs   = x   + base * DIMC;
        float*       outs = out + base * DIMC;
        dim3 g1(36, S / 64);
        gemm_f32<<<g1, 256, 0, stream>>>(xs, wh, bh, qkvws, NQKV);
        headattn<<<S / 4, 256, 0, stream>>>(qkvws, sumws, 0);
        gemm_f32<<<g1, 256, 0, stream>>>(xs, ww, bw, qkvws, NQKV);
        headattn<<<S / 4, 256, 0, stream>>>(qkvws, sumws, 1);
        dim3 g2(12, S / 64);
        gemm_f32<<<g2, 256, 0, stream>>>(sumws, wp, bp, outs, DIMC);
    }
}

// Round 5
// 790.349 us; speedup vs baseline: 6.6646x; 6.6646x over previous
//
#include <hip/hip_runtime.h>

typedef unsigned short u16;
typedef unsigned int u32;
typedef __attribute__((ext_vector_type(8))) short short8;
typedef __attribute__((ext_vector_type(4))) float f32x4;

#define DIMC 768
#define NQKV 2304
#define NPOS 32768

__device__ __forceinline__ float b2f(u16 u) {
    union { u32 i; float f; } c; c.i = ((u32)u) << 16; return c.f;
}
__device__ __forceinline__ u16 f2b(float f) {
    union { float f; u32 i; } c; c.f = f;
    u32 r = c.i + 0x7fffu + ((c.i >> 16) & 1u);
    return (u16)(r >> 16);
}

// async global->LDS, 16B per lane; lds dst must be the wave-uniform base
__device__ __forceinline__ void gl_lds16(const void* g, void* l) {
    __builtin_amdgcn_global_load_lds(
        (const __attribute__((address_space(1))) void*)g,
        (__attribute__((address_space(3))) void*)l, 16, 0, 0);
}

// ---- fp32 -> bf16 elementwise (x) ----
__global__ __launch_bounds__(256) void cvt_bf16(
    const float* __restrict__ in, u16* __restrict__ out, int n4)
{
    int i = blockIdx.x * 256 + threadIdx.x;
    if (i >= n4) return;
    float4 v = ((const float4*)in)[i];
    ushort4 o;
    o.x = f2b(v.x); o.y = f2b(v.y); o.z = f2b(v.z); o.w = f2b(v.w);
    ((ushort4*)out)[i] = o;
}

// ---- fp32 W[768][N] -> bf16 WT[N][768] (transpose + convert), 64x64 tiles ----
__global__ __launch_bounds__(256) void cvt_wT(
    const float* __restrict__ W0, const float* __restrict__ W1,
    const float* __restrict__ W2,
    u16* __restrict__ T0, u16* __restrict__ T1, u16* __restrict__ T2)
{
    const int z = blockIdx.z;
    const float* W = (z == 0) ? W0 : (z == 1) ? W1 : W2;
    u16* WT = (z == 0) ? T0 : (z == 1) ? T1 : T2;
    const int N = (z == 2) ? 768 : 2304;
    const int nb = blockIdx.x, kb = blockIdx.y;
    if (nb * 64 >= N) return;                       // block-uniform
    __shared__ u16 T[64][65];
    const int t = threadIdx.x, sr = t >> 2, sc = t & 3;
    {   // read W rows k=kb*64+sr, cols nb*64 + sc*16 .. +16
        const float4* p = (const float4*)(W + (size_t)(kb * 64 + sr) * N + nb * 64 + sc * 16);
        float4 a0 = p[0], a1 = p[1], a2 = p[2], a3 = p[3];
        float vv[16] = {a0.x, a0.y, a0.z, a0.w, a1.x, a1.y, a1.z, a1.w,
                        a2.x, a2.y, a2.z, a2.w, a3.x, a3.y, a3.z, a3.w};
        #pragma unroll
        for (int i = 0; i < 16; ++i)
            T[sc * 16 + i][sr] = f2b(vv[i]);
    }
    __syncthreads();
    {   // write WT row n=nb*64+sr, cols k=kb*64 + sc*16 .. +16
        u16 vv[16];
        #pragma unroll
        for (int i = 0; i < 16; ++i) vv[i] = T[sr][sc * 16 + i];
        uint4 p0, p1;
        p0.x = vv[0] | ((u32)vv[1] << 16);  p0.y = vv[2] | ((u32)vv[3] << 16);
        p0.z = vv[4] | ((u32)vv[5] << 16);  p0.w = vv[6] | ((u32)vv[7] << 16);
        p1.x = vv[8] | ((u32)vv[9] << 16);  p1.y = vv[10] | ((u32)vv[11] << 16);
        p1.z = vv[12] | ((u32)vv[13] << 16); p1.w = vv[14] | ((u32)vv[15] << 16);
        u16* q = WT + (size_t)(nb * 64 + sr) * DIMC + kb * 64 + sc * 16;
        *(uint4*)q = p0;
        *(uint4*)(q + 8) = p1;
    }
}

// ---- MFMA GEMM: C[M][ldn] = A_bf16[M][768] @ (BT_bf16[N][768])^T + bias ----
// 128x128 tile/block, 4 waves in 2x2, each wave 4x4 mfma_16x16x32 tiles, BK=32.
// c_is_f32: 1 -> C fp32, 0 -> C bf16.
__global__ __launch_bounds__(256) void gemm_mfma(
    const u16* __restrict__ A, const u16* __restrict__ BT,
    const float* __restrict__ bias, void* __restrict__ C,
    int ldn, int c_is_f32)
{
    __shared__ __align__(16) u16 As[128 * 32];  // [m][k] ld=32
    __shared__ __align__(16) u16 Bs[128 * 32];  // [n][k] ld=32
    const int t  = threadIdx.x;
    const int w  = t >> 6, l = t & 63;
    const int wm = w >> 1, wn = w & 1;
    const int lr = l & 15, lq = l >> 4;
    const int r  = t >> 2;                 // staging row within 64
    const int cc = (t & 3) * 8;            // staging k-chunk (8 bf16 = 16B)
    const int nBase = blockIdx.x * 128, mBase = blockIdx.y * 128;

    f32x4 acc[4][4];
    #pragma unroll
    for (int mt = 0; mt < 4; ++mt)
        #pragma unroll
        for (int nt = 0; nt < 4; ++nt)
            acc[mt][nt] = (f32x4){0.f, 0.f, 0.f, 0.f};

    const u16* a0 = A  + (size_t)(mBase +      r) * DIMC + cc;
    const u16* a1 = A  + (size_t)(mBase + 64 + r) * DIMC + cc;
    const u16* b0 = BT + (size_t)(nBase +      r) * DIMC + cc;
    const u16* b1 = BT + (size_t)(nBase + 64 + r) * DIMC + cc;
    u16* dA0 = As +        w * 512;        // wave-uniform LDS bases (u16 elems)
    u16* dA1 = As + 2048 + w * 512;
    u16* dB0 = Bs +        w * 512;
    u16* dB1 = Bs + 2048 + w * 512;

    for (int kb = 0; kb < 24; ++kb) {
        __syncthreads();
        gl_lds16(a0 + kb * 32, dA0);
        gl_lds16(a1 + kb * 32, dA1);
        gl_lds16(b0 + kb * 32, dB0);
        gl_lds16(b1 + kb * 32, dB1);
        __syncthreads();                   // drains vmcnt (global_load_lds) too
        short8 af[4], bf[4];
        #pragma unroll
        for (int i = 0; i < 4; ++i) {
            af[i] = *(const short8*)&As[(wm * 64 + i * 16 + lr) * 32 + lq * 8];
            bf[i] = *(const short8*)&Bs[(wn * 64 + i * 16 + lr) * 32 + lq * 8];
        }
        #pragma unroll
        for (int mt = 0; mt < 4; ++mt)
            #pragma unroll
            for (int nt = 0; nt < 4; ++nt)
                acc[mt][nt] = __builtin_amdgcn_mfma_f32_16x16x32_bf16(
                    af[mt], bf[nt], acc[mt][nt], 0, 0, 0);
    }
    // epilogue: C/D layout col=lane&15, row=(lane>>4)*4+reg (m89-verified)
    #pragma unroll
    for (int nt = 0; nt < 4; ++nt) {
        const int col = nBase + wn * 64 + nt * 16 + lr;
        const float bb = bias[col];
        #pragma unroll
        for (int mt = 0; mt < 4; ++mt) {
            const int row = mBase + wm * 64 + mt * 16 + lq * 4;
            #pragma unroll
            for (int rg = 0; rg < 4; ++rg) {
                float v = acc[mt][nt][rg] + bb;
                size_t idx = (size_t)(row + rg) * ldn + col;
                if (c_is_f32) ((float*)C)[idx] = v;
                else          ((u16*)C)[idx]   = f2b(v);
            }
        }
    }
}

// ---- head-attention per position (bf16 qkv in, bf16 sum out) ----
// qkv row = [q(12x64)|k(12x64)|v(12x64)]; S=0.125*qk^T (12x12), softmax over g,
// out[h*64+d] = sum_g A[h,g] v[g*64+d]. One wave/position, 4 positions/block.
__global__ __launch_bounds__(256) void headattn(
    const u16* __restrict__ qkv, u16* __restrict__ sum, int accumulate)
{
    __shared__ float qs[4][12 * 65];
    __shared__ float ks[4][12 * 65];
    __shared__ float vs[4][12 * 65];
    __shared__ float Sld[4][144];
    const int t = threadIdx.x, wv = t >> 6, lane = t & 63;
    const int p = blockIdx.x * 4 + wv;
    const u16* row = qkv + (size_t)p * NQKV;

    #pragma unroll
    for (int j = 0; j < 9; ++j) {
        int u2 = lane + 64 * j;                    // 0..575, 4 bf16 each
        uint2 d2 = *(const uint2*)(row + u2 * 4);
        int c = u2 * 4;
        int s = c / 768, rr = c % 768;
        int h = rr >> 6, d = rr & 63;
        float* dst = (s == 0) ? qs[wv] : (s == 1) ? ks[wv] : vs[wv];
        dst[h * 65 + d + 0] = b2f((u16)(d2.x & 0xffffu));
        dst[h * 65 + d + 1] = b2f((u16)(d2.x >> 16));
        dst[h * 65 + d + 2] = b2f((u16)(d2.y & 0xffffu));
        dst[h * 65 + d + 3] = b2f((u16)(d2.y >> 16));
    }
    __syncthreads();
    for (int e = lane; e < 144; e += 64) {
        int h = e / 12, g = e - h * 12;
        float s = 0.f;
        #pragma unroll 8
        for (int d = 0; d < 64; ++d)
            s = fmaf(qs[wv][h * 65 + d], ks[wv][g * 65 + d], s);
        Sld[wv][e] = s * 0.125f;
    }
    __syncthreads();
    if (lane < 12) {
        float m = -1e30f;
        #pragma unroll
        for (int g = 0; g < 12; ++g) m = fmaxf(m, Sld[wv][lane * 12 + g]);
        float ex[12]; float ssum = 0.f;
        #pragma unroll
        for (int g = 0; g < 12; ++g) { ex[g] = __expf(Sld[wv][lane * 12 + g] - m); ssum += ex[g]; }
        float inv = 1.f / ssum;
        #pragma unroll
        for (int g = 0; g < 12; ++g) Sld[wv][lane * 12 + g] = ex[g] * inv;
    }
    __syncthreads();
    u16* orow = sum + (size_t)p * DIMC;
    #pragma unroll
    for (int h = 0; h < 12; ++h) {
        float o = 0.f;
        #pragma unroll
        for (int g = 0; g < 12; ++g)
            o = fmaf(Sld[wv][h * 12 + g], vs[wv][g * 65 + lane], o);
        int idx = h * 64 + lane;
        if (accumulate) o += b2f(orow[idx]);
        orow[idx] = f2b(o);
    }
}

extern "C" void kernel_launch(void* const* d_in, const int* in_sizes, int n_in,
                              void* d_out, int out_size, void* d_ws, size_t ws_size,
                              hipStream_t stream) {
    const float* x  = (const float*)d_in[0];
    const float* wh = (const float*)d_in[1];
    const float* bh = (const float*)d_in[2];
    const float* ww = (const float*)d_in[3];
    const float* bw = (const float*)d_in[4];
    const float* wp = (const float*)d_in[5];
    const float* bp = (const float*)d_in[6];
    float* out = (float*)d_out;

    // ws (u16 elems): xb 25165824 | whT 1769472 | wwT 1769472 | wpT 589824 |
    //                 qkv 75497472 | sumb 25165824   => ~260 MB (ws >= 402 MB known)
    u16* xb   = (u16*)d_ws;
    u16* whT  = xb   + 25165824;
    u16* wwT  = whT  + 1769472;
    u16* wpT  = wwT  + 1769472;
    u16* qkvb = wpT  + 589824;
    u16* sumb = qkvb + 75497472;

    // conversions
    cvt_bf16<<<24576, 256, 0, stream>>>(x, xb, 6291456);
    dim3 wg(36, 12, 3);
    cvt_wT<<<wg, 256, 0, stream>>>(wh, ww, wp, whT, wwT, wpT);

    dim3 gq(NQKV / 128, NPOS / 128);      // (18, 256)
    dim3 gp(DIMC / 128, NPOS / 128);      // (6, 256)

    gemm_mfma<<<gq, 256, 0, stream>>>(xb, whT, bh, qkvb, NQKV, 0);
    headattn<<<NPOS / 4, 256, 0, stream>>>(qkvb, sumb, 0);
    gemm_mfma<<<gq, 256, 0, stream>>>(xb, wwT, bw, qkvb, NQKV, 0);
    headattn<<<NPOS / 4, 256, 0, stream>>>(qkvb, sumb, 1);
    gemm_mfma<<<gp, 256, 0, stream>>>(sumb, wpT, bp, out, DIMC, 1);
}